// Round 23
// baseline (566.260 us; speedup 1.0000x reference)
//
#include <hip/hip_runtime.h>

typedef unsigned int u32;
typedef unsigned short u16;
typedef __attribute__((ext_vector_type(8))) __bf16 bf16x8;
typedef __attribute__((ext_vector_type(4))) float f32x4;

#define MFMA(a,b,c) __builtin_amdgcn_mfma_f32_16x16x32_bf16(a,b,c,0,0,0)

__device__ __forceinline__ float bf2f(u16 v){ return __uint_as_float(((u32)v) << 16); }
__device__ __forceinline__ u16 f2bf(float f){
  u32 u = __float_as_uint(f);
  u += 0x7fffu + ((u >> 16) & 1u);
  return (u16)(u >> 16);
}
__device__ __forceinline__ u32 pack2(float a, float b){
  return (u32)f2bf(a) | ((u32)f2bf(b) << 16);
}
// tanh-form GELU (sigmoid form), fast rcp: total error ~5e-4 vs exact erf-GELU,
// below bf16 storage noise of h.
__device__ __forceinline__ float gelu_fast(float v){
  float t = v*(-1.5957691216f - 0.0713548163f*v*v);
  return v * __builtin_amdgcn_rcpf(1.f + __expf(t));
}

#define QSCALE 0.18257418583505536f

// ---------------- workspace (u16 units): fragment-major bf16 weights, HI plane only ----------------
// QKV padded to 48 nt (36 valid; q-plane pre-scaled by 1/sqrt(d)), Wp/W2 padded to 16 nt:
// every GEMM loads each weight fragment exactly once per block.
#define OQKV 0         // 48*6*512  = 147456
#define OWP  147456    // 16*6*512  =  49152
#define OW1  196608    // 48*6*512  = 147456
#define OW2  344064    // 16*23*512 = 188416
#define NW_TOT 532480

__global__ void swin_unpack(const float* __restrict__ qkvw, const float* __restrict__ projw,
                            const float* __restrict__ w1, const float* __restrict__ w2,
                            u16* __restrict__ ws){
  int idx = blockIdx.x * 256 + threadIdx.x;
  if (idx >= NW_TOT) return;
  float val = 0.f;
  if (idx < OWP){
    int t = idx, nt = t / 3072, r = t % 3072, kt = r >> 9, e = r & 511;
    int lane = e >> 3, j = e & 7;
    int n = nt*16 + (lane & 15), k = kt*32 + (lane >> 4)*8 + j;
    if (n < 576){
      int p = n / 192, c = n - p*192;
      if (c < 180 && k < 180){
        val = qkvw[k*540 + p*180 + c];
        if (p == 0) val *= QSCALE;         // fold q scale into weights
      }
    }
  } else if (idx < OW1){
    int t = idx - OWP, nt = t / 3072, r = t % 3072, kt = r >> 9, e = r & 511;
    int lane = e >> 3, j = e & 7;
    int n = nt*16 + (lane & 15), k = kt*32 + (lane >> 4)*8 + j;
    if (n < 180 && k < 180) val = projw[k*180 + n];
  } else if (idx < OW2){
    int t = idx - OW1, nt = t / 3072, r = t % 3072, kt = r >> 9, e = r & 511;
    int lane = e >> 3, j = e & 7;
    int n = nt*16 + (lane & 15), k = kt*32 + (lane >> 4)*8 + j;
    if (n < 720 && k < 180) val = w1[k*720 + n];
  } else {
    int t = idx - OW2, nt = t / 11776, r = t % 11776, kt = r >> 9, e = r & 511;
    int lane = e >> 3, j = e & 7;
    int n = nt*16 + (lane & 15), k = kt*32 + (lane >> 4)*8 + j;
    if (n < 180 && k < 720) val = w2[k*180 + n];
  }
  ws[idx] = f2bf(val);
}

// ---------------- kernel 1: LN1 + QKV + attn + proj + residual (1024 thr, 16 waves = 4/SIMD) ----
#define A_Y   0        // 64 x 400B
#define A_Q   25600    // 64 x 400B (Q+K reused as fp32 RES[64][180] after attention)
#define A_K   51200    // 64 x 400B
#define A_VT  76800    // 192 x 144B = 27648
#define A_P   104448   // 16 waves x 2304B = 36864
#define A_RB  141312   // 64 ints  => total 141568

__global__ __launch_bounds__(1024, 1) void swin_attn(
    const float* __restrict__ x, const float* __restrict__ n1s, const float* __restrict__ n1b,
    const u16* __restrict__ ws, const float* __restrict__ qkvb,
    const float* __restrict__ projb, float* __restrict__ out){
  __shared__ __align__(16) char sm[141568];
  const int tid = threadIdx.x;
  const int w16 = tid >> 6, l = tid & 63, l15 = l & 15, lq = l >> 4;
  int* rb = (int*)(sm + A_RB);
  const f32x4 fz = {0.f, 0.f, 0.f, 0.f};
  float4 xv[3];                 // this thread's x slice (row w16*4+(l&3), col-quads lq4,+16,+32)
  const int r4 = l & 3, lq4 = l >> 2;
  const int myrow = w16*4 + r4;

  if (tid < 64){
    int wb = blockIdx.x;
    int b = wb >> 10, wy = (wb >> 5) & 31, wx = wb & 31;
    rb[tid] = b*65536 + (wy*8 + (tid>>3))*256 + (wx*8 + (tid&7));
  }
  // zero pads: Q/K head-pad cols h*32+{30,31}; Y cols 180..191
  for (int i = tid; i < 2304; i += 1024){
    int row = i / 36, t = i - row*36;
    if (t < 24){
      int buf = (t >= 12) ? A_K : A_Q; int tt = t % 12;
      *(u16*)(sm + buf + row*400 + ((tt>>1)*32 + 30 + (tt&1))*2) = 0;
    } else
      *(u16*)(sm + A_Y + row*400 + (180 + t - 24)*2) = 0;
  }
  __syncthreads();

  // ---- LN1: 16 waves x 4 rows, 16 lanes per row; x retained in registers ----
  {
    const float4* px = (const float4*)(x + (size_t)rb[myrow]*180);
    xv[0] = px[lq4];
    xv[1] = px[lq4 + 16];
    xv[2] = (lq4 < 13) ? px[lq4 + 32] : make_float4(0.f,0.f,0.f,0.f);
    float s = 0.f, ss = 0.f;
    #pragma unroll
    for (int i = 0; i < 3; ++i){
      s  += xv[i].x + xv[i].y + xv[i].z + xv[i].w;
      ss += xv[i].x*xv[i].x + xv[i].y*xv[i].y + xv[i].z*xv[i].z + xv[i].w*xv[i].w;
    }
    #pragma unroll
    for (int m = 4; m <= 32; m <<= 1){ s += __shfl_xor(s, m); ss += __shfl_xor(ss, m); }
    float mean = s * (1.f/180.f);
    float rstd = rsqrtf(ss * (1.f/180.f) - mean*mean + 1e-5f);
    u32* yr = (u32*)(sm + A_Y + myrow*400);
    const float4* s4 = (const float4*)n1s;
    const float4* b4 = (const float4*)n1b;
    #pragma unroll
    for (int i = 0; i < 3; ++i){
      if (i < 2 || lq4 < 13){
        int c4 = lq4 + 16*i;
        float4 sc = s4[c4], bi = b4[c4];
        float e0 = (xv[i].x - mean)*rstd*sc.x + bi.x;
        float e1 = (xv[i].y - mean)*rstd*sc.y + bi.y;
        float e2 = (xv[i].z - mean)*rstd*sc.z + bi.z;
        float e3 = (xv[i].w - mean)*rstd*sc.w + bi.w;
        yr[c4*2]     = pack2(e0, e1);
        yr[c4*2 + 1] = pack2(e2, e3);
      }
    }
  }
  __syncthreads();

  // ---- QKV: wave w16 owns 3 nt (48 padded, 36 valid), all 64 tokens; 1-deep prefetch ----
  // q-plane weights pre-scaled; bias scaled here once per column.
  {
    const int ntb = w16*3;
    f32x4 acc[4][3];
    #pragma unroll
    for (int m = 0; m < 4; ++m)
      #pragma unroll
      for (int i = 0; i < 3; ++i) acc[m][i] = fz;
    bf16x8 bcur[3];
    #pragma unroll
    for (int i = 0; i < 3; ++i)
      bcur[i] = *(const bf16x8*)(ws + OQKV + ((ntb+i)*6 + 0)*512 + l*8);
    #pragma unroll
    for (int kt = 0; kt < 6; ++kt){
      bf16x8 bnxt[3];
      if (kt < 5){
        #pragma unroll
        for (int i = 0; i < 3; ++i)
          bnxt[i] = *(const bf16x8*)(ws + OQKV + ((ntb+i)*6 + kt + 1)*512 + l*8);
      }
      bf16x8 a[4];
      #pragma unroll
      for (int m = 0; m < 4; ++m)
        a[m] = *(const bf16x8*)(sm + A_Y + (m*16 + l15)*400 + kt*64 + lq*16);
      #pragma unroll
      for (int m = 0; m < 4; ++m)
        #pragma unroll
        for (int i = 0; i < 3; ++i)
          acc[m][i] = MFMA(a[m], bcur[i], acc[m][i]);
      if (kt < 5){
        #pragma unroll
        for (int i = 0; i < 3; ++i) bcur[i] = bnxt[i];
      }
    }
    #pragma unroll
    for (int i = 0; i < 3; ++i){
      int n = (ntb + i)*16 + l15;
      if (n < 576){
        int p = n / 192, c = n - p*192;
        if (c < 180){
          float bias = qkvb[p*180 + c];
          if (p == 0) bias *= QSCALE;
          int h = c / 30, d = c - h*30;
          int colp = h*32 + d;
          #pragma unroll
          for (int m = 0; m < 4; ++m)
            #pragma unroll
            for (int r = 0; r < 4; ++r){
              float val = acc[m][i][r] + bias;
              int tok = m*16 + lq*4 + r;
              if (p == 0)      *(u16*)(sm + A_Q + tok*400 + colp*2) = f2bf(val);
              else if (p == 1) *(u16*)(sm + A_K + tok*400 + colp*2) = f2bf(val);
              else             *(u16*)(sm + A_VT + colp*144 + tok*2) = f2bf(val);
            }
        }
      }
    }
  }
  __syncthreads();

  // ---- attention: 24 units (tq 0..3 x head 0..5) striped over 16 waves ----
  // P stored unnormalized (exp <= 1); per-row 1/sum applied to PV output.
  {
    for (int u = w16; u < 24; u += 16){
      const int tq = u & 3, h = u >> 2;
      bf16x8 aq = *(const bf16x8*)(sm + A_Q + (tq*16 + l15)*400 + h*64 + lq*16);
      f32x4 s[4];
      #pragma unroll
      for (int nt = 0; nt < 4; ++nt){
        bf16x8 bk = *(const bf16x8*)(sm + A_K + (nt*16 + l15)*400 + h*64 + lq*16);
        s[nt] = MFMA(aq, bk, fz);
      }
      float iv4[4];
      #pragma unroll
      for (int r = 0; r < 4; ++r){
        float mx = fmaxf(fmaxf(s[0][r], s[1][r]), fmaxf(s[2][r], s[3][r]));
        mx = fmaxf(mx, __shfl_xor(mx, 1));
        mx = fmaxf(mx, __shfl_xor(mx, 2));
        mx = fmaxf(mx, __shfl_xor(mx, 4));
        mx = fmaxf(mx, __shfl_xor(mx, 8));
        float e0 = __expf(s[0][r]-mx), e1 = __expf(s[1][r]-mx);
        float e2 = __expf(s[2][r]-mx), e3 = __expf(s[3][r]-mx);
        float sum = e0 + e1 + e2 + e3;
        sum += __shfl_xor(sum,1); sum += __shfl_xor(sum,2);
        sum += __shfl_xor(sum,4); sum += __shfl_xor(sum,8);
        iv4[r] = 1.f / sum;
        char* pr = sm + A_P + w16*2304 + (lq*4 + r)*144 + l15*2;
        *(u16*)(pr)      = f2bf(e0);
        *(u16*)(pr + 32) = f2bf(e1);
        *(u16*)(pr + 64) = f2bf(e2);
        *(u16*)(pr + 96) = f2bf(e3);
      }
      asm volatile("s_waitcnt lgkmcnt(0)" ::: "memory");
      f32x4 o0 = fz, o1 = fz;
      #pragma unroll
      for (int kt = 0; kt < 2; ++kt){
        bf16x8 aP  = *(const bf16x8*)(sm + A_P + w16*2304 + l15*144 + kt*64 + lq*16);
        bf16x8 bv0 = *(const bf16x8*)(sm + A_VT + (h*32 + l15)*144 + kt*64 + lq*16);
        bf16x8 bv1 = *(const bf16x8*)(sm + A_VT + (h*32 + 16 + l15)*144 + kt*64 + lq*16);
        o0 = MFMA(aP, bv0, o0);
        o1 = MFMA(aP, bv1, o1);
      }
      #pragma unroll
      for (int r = 0; r < 4; ++r){
        int tok = tq*16 + lq*4 + r;
        {
          int col = h*30 + l15;
          *(u16*)(sm + A_Y + tok*400 + col*2) = f2bf(o0[r] * iv4[r]);
        }
        if (l15 < 14){
          int col = h*30 + 16 + l15;
          *(u16*)(sm + A_Y + tok*400 + col*2) = f2bf(o1[r] * iv4[r]);
        }
      }
    }
  }
  __syncthreads();

  // ---- proj: wave w16 owns 1 nt (16 padded, 12 valid) x all 4 mt (load-once); 1-deep prefetch ----
  {
    f32x4 acc2[4];
    #pragma unroll
    for (int m = 0; m < 4; ++m) acc2[m] = fz;
    bf16x8 wb0 = *(const bf16x8*)(ws + OWP + (w16*6 + 0)*512 + l*8);
    #pragma unroll
    for (int kt = 0; kt < 6; ++kt){
      bf16x8 wbn;
      if (kt < 5) wbn = *(const bf16x8*)(ws + OWP + (w16*6 + kt + 1)*512 + l*8);
      bf16x8 a[4];
      #pragma unroll
      for (int m = 0; m < 4; ++m)
        a[m] = *(const bf16x8*)(sm + A_Y + (m*16 + l15)*400 + kt*64 + lq*16);
      #pragma unroll
      for (int m = 0; m < 4; ++m)
        acc2[m] = MFMA(a[m], wb0, acc2[m]);
      if (kt < 5) wb0 = wbn;
    }
    float* res = (float*)(sm + A_Q);
    int col = w16*16 + l15;
    if (col < 180){
      float bias = projb[col];
      #pragma unroll
      for (int m = 0; m < 4; ++m)
        #pragma unroll
        for (int r = 0; r < 4; ++r)
          res[(m*16 + lq*4 + r)*180 + col] = acc2[m][r] + bias;
    }
  }
  __syncthreads();

  // ---- residual write: out = RES + x (x from LN1 registers, no global re-read) ----
  {
    const float* res = (const float*)(sm + A_Q);
    const float4* rr = (const float4*)(res + myrow*180);
    float4* og = (float4*)(out + (size_t)rb[myrow]*180);
    float4 a0 = rr[lq4];
    a0.x += xv[0].x; a0.y += xv[0].y; a0.z += xv[0].z; a0.w += xv[0].w;
    og[lq4] = a0;
    float4 a1 = rr[lq4 + 16];
    a1.x += xv[1].x; a1.y += xv[1].y; a1.z += xv[1].z; a1.w += xv[1].w;
    og[lq4 + 16] = a1;
    if (lq4 < 13){
      float4 a2 = rr[lq4 + 32];
      a2.x += xv[2].x; a2.y += xv[2].y; a2.z += xv[2].z; a2.w += xv[2].w;
      og[lq4 + 32] = a2;
    }
  }
}

// ---------------- kernel 2: LN2 + MLP(fast GELU) + residual (1024 thr, 16 waves = 4/SIMD) ----
#define M_Y 0
#define M_G 25600   // 64 x 1552B

__global__ __launch_bounds__(1024, 1) void swin_mlp(
    const float* __restrict__ n2s, const float* __restrict__ n2b,
    const u16* __restrict__ ws, const float* __restrict__ b1, const float* __restrict__ b2,
    float* __restrict__ out){
  __shared__ __align__(16) char sm[124928];
  const int tid = threadIdx.x;
  const int w16 = tid >> 6, l = tid & 63, l15 = l & 15, lq = l >> 4;
  const size_t base = (size_t)blockIdx.x * (64*180);
  const f32x4 fz = {0.f, 0.f, 0.f, 0.f};
  float4 xv[3];                 // this thread's x2 slice, retained from LN2
  const int r4 = l & 3, lq4 = l >> 2;
  const int myrow = w16*4 + r4;

  // zero Y pad cols 180..191
  if (tid < 768){
    int row = tid / 12, col = 180 + tid % 12;
    *(u16*)(sm + M_Y + row*400 + col*2) = 0;
  }
  // ---- LN2: 16 waves x 4 rows, 16 lanes per row; x2 retained in registers ----
  {
    const float4* px = (const float4*)(out + base + (size_t)myrow*180);
    xv[0] = px[lq4];
    xv[1] = px[lq4 + 16];
    xv[2] = (lq4 < 13) ? px[lq4 + 32] : make_float4(0.f,0.f,0.f,0.f);
    float s = 0.f, ss = 0.f;
    #pragma unroll
    for (int i = 0; i < 3; ++i){
      s  += xv[i].x + xv[i].y + xv[i].z + xv[i].w;
      ss += xv[i].x*xv[i].x + xv[i].y*xv[i].y + xv[i].z*xv[i].z + xv[i].w*xv[i].w;
    }
    #pragma unroll
    for (int m = 4; m <= 32; m <<= 1){ s += __shfl_xor(s, m); ss += __shfl_xor(ss, m); }
    float mean = s * (1.f/180.f);
    float rstd = rsqrtf(ss * (1.f/180.f) - mean*mean + 1e-5f);
    u32* yr = (u32*)(sm + M_Y + myrow*400);
    const float4* s4 = (const float4*)n2s;
    const float4* b4 = (const float4*)n2b;
    #pragma unroll
    for (int i = 0; i < 3; ++i){
      if (i < 2 || lq4 < 13){
        int c4 = lq4 + 16*i;
        float4 sc = s4[c4], bi = b4[c4];
        float e0 = (xv[i].x - mean)*rstd*sc.x + bi.x;
        float e1 = (xv[i].y - mean)*rstd*sc.y + bi.y;
        float e2 = (xv[i].z - mean)*rstd*sc.z + bi.z;
        float e3 = (xv[i].w - mean)*rstd*sc.w + bi.w;
        yr[c4*2]     = pack2(e0, e1);
        yr[c4*2 + 1] = pack2(e2, e3);
      }
    }
  }
  __syncthreads();

  // ---- GEMM1 + fast GELU: wave w16 owns 3 nt (48 total = 768 cols); 1-deep prefetch ----
  {
    const int ntb = w16*3;
    f32x4 acc[4][3];
    #pragma unroll
    for (int m = 0; m < 4; ++m)
      #pragma unroll
      for (int i = 0; i < 3; ++i) acc[m][i] = fz;
    bf16x8 bcur[3];
    #pragma unroll
    for (int i = 0; i < 3; ++i)
      bcur[i] = *(const bf16x8*)(ws + OW1 + ((ntb+i)*6 + 0)*512 + l*8);
    #pragma unroll
    for (int kt = 0; kt < 6; ++kt){
      bf16x8 bnxt[3];
      if (kt < 5){
        #pragma unroll
        for (int i = 0; i < 3; ++i)
          bnxt[i] = *(const bf16x8*)(ws + OW1 + ((ntb+i)*6 + kt + 1)*512 + l*8);
      }
      bf16x8 a[4];
      #pragma unroll
      for (int m = 0; m < 4; ++m)
        a[m] = *(const bf16x8*)(sm + M_Y + (m*16 + l15)*400 + kt*64 + lq*16);
      #pragma unroll
      for (int m = 0; m < 4; ++m)
        #pragma unroll
        for (int i = 0; i < 3; ++i)
          acc[m][i] = MFMA(a[m], bcur[i], acc[m][i]);
      if (kt < 5){
        #pragma unroll
        for (int i = 0; i < 3; ++i) bcur[i] = bnxt[i];
      }
    }
    #pragma unroll
    for (int i = 0; i < 3; ++i){
      int gc = (ntb + i)*16 + l15;   // 0..767
      float bias = (gc < 720) ? b1[gc] : 0.f;
      #pragma unroll
      for (int m = 0; m < 4; ++m)
        #pragma unroll
        for (int r = 0; r < 4; ++r){
          float v = acc[m][i][r] + bias;
          float gel = (gc < 720) ? gelu_fast(v) : 0.f;
          *(u16*)(sm + M_G + (m*16 + lq*4 + r)*1552 + gc*2) = f2bf(gel);
        }
    }
  }
  __syncthreads();

  // ---- GEMM2: 23 kt; wave w16 owns 1 nt (of 16 padded) x 4 mt; 2-deep prefetch ----
  {
    f32x4 acc2[4];
    #pragma unroll
    for (int m = 0; m < 4; ++m) acc2[m] = fz;
    bf16x8 wb0, wb1;
    wb0 = *(const bf16x8*)(ws + OW2 + (w16*23 + 0)*512 + l*8);
    wb1 = *(const bf16x8*)(ws + OW2 + (w16*23 + 1)*512 + l*8);
    for (int kt = 0; kt < 23; ++kt){
      int ktn = (kt < 21) ? kt + 2 : 22;
      bf16x8 wbn = *(const bf16x8*)(ws + OW2 + (w16*23 + ktn)*512 + l*8);
      bf16x8 a[4];
      #pragma unroll
      for (int m = 0; m < 4; ++m)
        a[m] = *(const bf16x8*)(sm + M_G + (m*16 + l15)*1552 + kt*64 + lq*16);
      #pragma unroll
      for (int m = 0; m < 4; ++m)
        acc2[m] = MFMA(a[m], wb0, acc2[m]);
      wb0 = wb1; wb1 = wbn;
    }
    __syncthreads();   // all G reads done before RES overwrites it

    float* res = (float*)(sm + M_G);
    int col = w16*16 + l15;
    if (col < 180){
      float bias = b2[col];
      #pragma unroll
      for (int m = 0; m < 4; ++m)
        #pragma unroll
        for (int r = 0; r < 4; ++r)
          res[(m*16 + lq*4 + r)*180 + col] = acc2[m][r] + bias;
    }
  }
  __syncthreads();

  // ---- residual write: out = RES + x2 (x2 from LN2 registers, no global re-read) ----
  {
    const float* res = (const float*)(sm + M_G);
    const float4* rr = (const float4*)(res + myrow*180);
    float4* og = (float4*)(out + base + (size_t)myrow*180);
    float4 a0 = rr[lq4];
    a0.x += xv[0].x; a0.y += xv[0].y; a0.z += xv[0].z; a0.w += xv[0].w;
    og[lq4] = a0;
    float4 a1 = rr[lq4 + 16];
    a1.x += xv[1].x; a1.y += xv[1].y; a1.z += xv[1].z; a1.w += xv[1].w;
    og[lq4 + 16] = a1;
    if (lq4 < 13){
      float4 a2 = rr[lq4 + 32];
      a2.x += xv[2].x; a2.y += xv[2].y; a2.z += xv[2].z; a2.w += xv[2].w;
      og[lq4 + 32] = a2;
    }
  }
}

extern "C" void kernel_launch(void* const* d_in, const int* in_sizes, int n_in,
                              void* d_out, int out_size, void* d_ws, size_t ws_size,
                              hipStream_t stream){
  const float* x     = (const float*)d_in[0];
  const float* n1s   = (const float*)d_in[1];
  const float* n1b   = (const float*)d_in[2];
  const float* qkvw  = (const float*)d_in[3];
  const float* qkvb  = (const float*)d_in[4];
  const float* projw = (const float*)d_in[5];
  const float* projb = (const float*)d_in[6];
  const float* n2s   = (const float*)d_in[7];
  const float* n2b   = (const float*)d_in[8];
  const float* w1    = (const float*)d_in[9];
  const float* b1    = (const float*)d_in[10];
  const float* w2    = (const float*)d_in[11];
  const float* b2    = (const float*)d_in[12];
  float* outp = (float*)d_out;
  u16* wsp = (u16*)d_ws;

  swin_unpack<<<(NW_TOT + 255) / 256, 256, 0, stream>>>(qkvw, projw, w1, w2, wsp);
  swin_attn<<<4096, 1024, 0, stream>>>(x, n1s, n1b, wsp, qkvb, projb, outp);
  swin_mlp<<<4096, 1024, 0, stream>>>(n2s, n2b, wsp, b1, b2, outp);
}

// Round 24
// 564.230 us; speedup vs baseline: 1.0036x; 1.0036x over previous
//
#include <hip/hip_runtime.h>

typedef unsigned int u32;
typedef unsigned short u16;
typedef __attribute__((ext_vector_type(8))) __bf16 bf16x8;
typedef __attribute__((ext_vector_type(4))) float f32x4;

#define MFMA(a,b,c) __builtin_amdgcn_mfma_f32_16x16x32_bf16(a,b,c,0,0,0)

__device__ __forceinline__ float bf2f(u16 v){ return __uint_as_float(((u32)v) << 16); }
__device__ __forceinline__ u16 f2bf(float f){
  u32 u = __float_as_uint(f);
  u += 0x7fffu + ((u >> 16) & 1u);
  return (u16)(u >> 16);
}
__device__ __forceinline__ u32 pack2(float a, float b){
  return (u32)f2bf(a) | ((u32)f2bf(b) << 16);
}
// tanh-form GELU (sigmoid form), fast rcp: total error ~5e-4 vs exact erf-GELU,
// below bf16 storage noise of h.
__device__ __forceinline__ float gelu_fast(float v){
  float t = v*(-1.5957691216f - 0.0713548163f*v*v);
  return v * __builtin_amdgcn_rcpf(1.f + __expf(t));
}

#define QSCALE 0.18257418583505536f

// ---------------- workspace (u16 units): fragment-major bf16 weights, HI plane only ----------------
// QKV padded to 48 nt (36 valid; q-plane pre-scaled by 1/sqrt(d)), Wp/W2 padded to 16 nt:
// every GEMM loads each weight fragment exactly once per block.
#define OQKV 0         // 48*6*512  = 147456
#define OWP  147456    // 16*6*512  =  49152
#define OW1  196608    // 48*6*512  = 147456
#define OW2  344064    // 16*23*512 = 188416
#define NW_TOT 532480

__global__ void swin_unpack(const float* __restrict__ qkvw, const float* __restrict__ projw,
                            const float* __restrict__ w1, const float* __restrict__ w2,
                            u16* __restrict__ ws){
  int idx = blockIdx.x * 256 + threadIdx.x;
  if (idx >= NW_TOT) return;
  float val = 0.f;
  if (idx < OWP){
    int t = idx, nt = t / 3072, r = t % 3072, kt = r >> 9, e = r & 511;
    int lane = e >> 3, j = e & 7;
    int n = nt*16 + (lane & 15), k = kt*32 + (lane >> 4)*8 + j;
    if (n < 576){
      int p = n / 192, c = n - p*192;
      if (c < 180 && k < 180){
        val = qkvw[k*540 + p*180 + c];
        if (p == 0) val *= QSCALE;         // fold q scale into weights
      }
    }
  } else if (idx < OW1){
    int t = idx - OWP, nt = t / 3072, r = t % 3072, kt = r >> 9, e = r & 511;
    int lane = e >> 3, j = e & 7;
    int n = nt*16 + (lane & 15), k = kt*32 + (lane >> 4)*8 + j;
    if (n < 180 && k < 180) val = projw[k*180 + n];
  } else if (idx < OW2){
    int t = idx - OW1, nt = t / 3072, r = t % 3072, kt = r >> 9, e = r & 511;
    int lane = e >> 3, j = e & 7;
    int n = nt*16 + (lane & 15), k = kt*32 + (lane >> 4)*8 + j;
    if (n < 720 && k < 180) val = w1[k*720 + n];
  } else {
    int t = idx - OW2, nt = t / 11776, r = t % 11776, kt = r >> 9, e = r & 511;
    int lane = e >> 3, j = e & 7;
    int n = nt*16 + (lane & 15), k = kt*32 + (lane >> 4)*8 + j;
    if (n < 180 && k < 720) val = w2[k*180 + n];
  }
  ws[idx] = f2bf(val);
}

// ---------------- kernel 1: LN1 + QKV + attn + proj + residual (768 thr, 12 waves = 3/SIMD) ----
// 768-thread geometry (thrice measured ~230us draws) + all accumulated work cuts:
// load-once proj (12 nt / 12 waves exact), register-kept x residual, per-thread
// rowbase (no rb LDS, one fewer barrier), QSCALE fold, deferred softmax norm.
#define A_Y   0        // 64 x 400B
#define A_Q   25600    // 64 x 400B (Q+K reused as fp32 RES[64][180] after attention)
#define A_K   51200    // 64 x 400B
#define A_VT  76800    // 192 x 144B = 27648
#define A_P   104448   // 12 waves x 2304B = 27648  => total 132096

__global__ __launch_bounds__(768, 1) void swin_attn(
    const float* __restrict__ x, const float* __restrict__ n1s, const float* __restrict__ n1b,
    const u16* __restrict__ ws, const float* __restrict__ qkvb,
    const float* __restrict__ projb, float* __restrict__ out){
  __shared__ __align__(16) char sm[132096];
  const int tid = threadIdx.x;
  const int w12 = tid >> 6, l = tid & 63, l15 = l & 15, lq = l >> 4;
  const f32x4 fz = {0.f, 0.f, 0.f, 0.f};
  const int wb = blockIdx.x;
  const int bb = wb >> 10, wy = (wb >> 5) & 31, wx = wb & 31;
  // LN/residual mapping (waves 0..7): row myrow, 8 lanes per row
  const int r3 = l & 7, lq2 = l >> 3;
  const int myrow = w12*8 + r3;
  const size_t myglob = (size_t)(bb*65536 + (wy*8 + (myrow >> 3))*256 + wx*8 + (myrow & 7)) * 180;
  float4 xv[6];   // this thread's x slice, retained from LN1 (waves 0..7)

  // zero pads: Q/K head-pad cols h*32+{30,31}; Y cols 180..191
  for (int i = tid; i < 2304; i += 768){
    int row = i / 36, t = i - row*36;
    if (t < 24){
      int buf = (t >= 12) ? A_K : A_Q; int tt = t % 12;
      *(u16*)(sm + buf + row*400 + ((tt>>1)*32 + 30 + (tt&1))*2) = 0;
    } else
      *(u16*)(sm + A_Y + row*400 + (180 + t - 24)*2) = 0;
  }

  // ---- LN1: waves 0..7, 8 rows each, 8 lanes per row; x retained in registers ----
  if (w12 < 8){
    const float4* px = (const float4*)(x + myglob);
    #pragma unroll
    for (int i = 0; i < 5; ++i) xv[i] = px[lq2 + 8*i];
    xv[5] = (lq2 < 5) ? px[lq2 + 40] : make_float4(0.f,0.f,0.f,0.f);
    float s = 0.f, ss = 0.f;
    #pragma unroll
    for (int i = 0; i < 6; ++i){
      s  += xv[i].x + xv[i].y + xv[i].z + xv[i].w;
      ss += xv[i].x*xv[i].x + xv[i].y*xv[i].y + xv[i].z*xv[i].z + xv[i].w*xv[i].w;
    }
    #pragma unroll
    for (int m = 8; m <= 32; m <<= 1){ s += __shfl_xor(s, m); ss += __shfl_xor(ss, m); }
    float mean = s * (1.f/180.f);
    float rstd = rsqrtf(ss * (1.f/180.f) - mean*mean + 1e-5f);
    u32* yr = (u32*)(sm + A_Y + myrow*400);
    const float4* s4 = (const float4*)n1s;
    const float4* b4 = (const float4*)n1b;
    #pragma unroll
    for (int i = 0; i < 6; ++i){
      if (i < 5 || lq2 < 5){
        int c4 = lq2 + 8*i;
        float4 sc = s4[c4], bi = b4[c4];
        float e0 = (xv[i].x - mean)*rstd*sc.x + bi.x;
        float e1 = (xv[i].y - mean)*rstd*sc.y + bi.y;
        float e2 = (xv[i].z - mean)*rstd*sc.z + bi.z;
        float e3 = (xv[i].w - mean)*rstd*sc.w + bi.w;
        yr[c4*2]     = pack2(e0, e1);
        yr[c4*2 + 1] = pack2(e2, e3);
      }
    }
  }
  __syncthreads();

  // ---- QKV: wave w12 owns 3 nt (36 exact), all 64 tokens; 1-deep prefetch; load-once ----
  {
    const int ntb = w12*3;
    f32x4 acc[4][3];
    #pragma unroll
    for (int m = 0; m < 4; ++m)
      #pragma unroll
      for (int i = 0; i < 3; ++i) acc[m][i] = fz;
    bf16x8 bcur[3];
    #pragma unroll
    for (int i = 0; i < 3; ++i)
      bcur[i] = *(const bf16x8*)(ws + OQKV + ((ntb+i)*6 + 0)*512 + l*8);
    #pragma unroll
    for (int kt = 0; kt < 6; ++kt){
      bf16x8 bnxt[3];
      if (kt < 5){
        #pragma unroll
        for (int i = 0; i < 3; ++i)
          bnxt[i] = *(const bf16x8*)(ws + OQKV + ((ntb+i)*6 + kt + 1)*512 + l*8);
      }
      bf16x8 a[4];
      #pragma unroll
      for (int m = 0; m < 4; ++m)
        a[m] = *(const bf16x8*)(sm + A_Y + (m*16 + l15)*400 + kt*64 + lq*16);
      #pragma unroll
      for (int m = 0; m < 4; ++m)
        #pragma unroll
        for (int i = 0; i < 3; ++i)
          acc[m][i] = MFMA(a[m], bcur[i], acc[m][i]);
      if (kt < 5){
        #pragma unroll
        for (int i = 0; i < 3; ++i) bcur[i] = bnxt[i];
      }
    }
    #pragma unroll
    for (int i = 0; i < 3; ++i){
      int n = (ntb + i)*16 + l15;     // < 576 always
      int p = n / 192, c = n - p*192;
      if (c < 180){
        float bias = qkvb[p*180 + c];
        if (p == 0) bias *= QSCALE;
        int h = c / 30, d = c - h*30;
        int colp = h*32 + d;
        #pragma unroll
        for (int m = 0; m < 4; ++m)
          #pragma unroll
          for (int r = 0; r < 4; ++r){
            float val = acc[m][i][r] + bias;
            int tok = m*16 + lq*4 + r;
            if (p == 0)      *(u16*)(sm + A_Q + tok*400 + colp*2) = f2bf(val);
            else if (p == 1) *(u16*)(sm + A_K + tok*400 + colp*2) = f2bf(val);
            else             *(u16*)(sm + A_VT + colp*144 + tok*2) = f2bf(val);
          }
      }
    }
  }
  __syncthreads();

  // ---- attention: 24 units (tq 0..3 x head 0..5), exactly 2 per wave (balanced) ----
  // P stored unnormalized; per-row 1/sum applied to PV output.
  {
    for (int u = w12; u < 24; u += 12){
      const int tq = u & 3, h = u >> 2;
      bf16x8 aq = *(const bf16x8*)(sm + A_Q + (tq*16 + l15)*400 + h*64 + lq*16);
      f32x4 s[4];
      #pragma unroll
      for (int nt = 0; nt < 4; ++nt){
        bf16x8 bk = *(const bf16x8*)(sm + A_K + (nt*16 + l15)*400 + h*64 + lq*16);
        s[nt] = MFMA(aq, bk, fz);
      }
      float iv4[4];
      #pragma unroll
      for (int r = 0; r < 4; ++r){
        float mx = fmaxf(fmaxf(s[0][r], s[1][r]), fmaxf(s[2][r], s[3][r]));
        mx = fmaxf(mx, __shfl_xor(mx, 1));
        mx = fmaxf(mx, __shfl_xor(mx, 2));
        mx = fmaxf(mx, __shfl_xor(mx, 4));
        mx = fmaxf(mx, __shfl_xor(mx, 8));
        float e0 = __expf(s[0][r]-mx), e1 = __expf(s[1][r]-mx);
        float e2 = __expf(s[2][r]-mx), e3 = __expf(s[3][r]-mx);
        float sum = e0 + e1 + e2 + e3;
        sum += __shfl_xor(sum,1); sum += __shfl_xor(sum,2);
        sum += __shfl_xor(sum,4); sum += __shfl_xor(sum,8);
        iv4[r] = 1.f / sum;
        char* pr = sm + A_P + w12*2304 + (lq*4 + r)*144 + l15*2;
        *(u16*)(pr)      = f2bf(e0);
        *(u16*)(pr + 32) = f2bf(e1);
        *(u16*)(pr + 64) = f2bf(e2);
        *(u16*)(pr + 96) = f2bf(e3);
      }
      asm volatile("s_waitcnt lgkmcnt(0)" ::: "memory");
      f32x4 o0 = fz, o1 = fz;
      #pragma unroll
      for (int kt = 0; kt < 2; ++kt){
        bf16x8 aP  = *(const bf16x8*)(sm + A_P + w12*2304 + l15*144 + kt*64 + lq*16);
        bf16x8 bv0 = *(const bf16x8*)(sm + A_VT + (h*32 + l15)*144 + kt*64 + lq*16);
        bf16x8 bv1 = *(const bf16x8*)(sm + A_VT + (h*32 + 16 + l15)*144 + kt*64 + lq*16);
        o0 = MFMA(aP, bv0, o0);
        o1 = MFMA(aP, bv1, o1);
      }
      #pragma unroll
      for (int r = 0; r < 4; ++r){
        int tok = tq*16 + lq*4 + r;
        {
          int col = h*30 + l15;
          *(u16*)(sm + A_Y + tok*400 + col*2) = f2bf(o0[r] * iv4[r]);
        }
        if (l15 < 14){
          int col = h*30 + 16 + l15;
          *(u16*)(sm + A_Y + tok*400 + col*2) = f2bf(o1[r] * iv4[r]);
        }
      }
    }
  }
  __syncthreads();

  // ---- proj: wave w12 owns 1 nt (12 nt exact, load-once) x all 4 mt; 1-deep prefetch ----
  {
    f32x4 acc2[4];
    #pragma unroll
    for (int m = 0; m < 4; ++m) acc2[m] = fz;
    bf16x8 wb0 = *(const bf16x8*)(ws + OWP + (w12*6 + 0)*512 + l*8);
    #pragma unroll
    for (int kt = 0; kt < 6; ++kt){
      bf16x8 wbn;
      if (kt < 5) wbn = *(const bf16x8*)(ws + OWP + (w12*6 + kt + 1)*512 + l*8);
      bf16x8 a[4];
      #pragma unroll
      for (int m = 0; m < 4; ++m)
        a[m] = *(const bf16x8*)(sm + A_Y + (m*16 + l15)*400 + kt*64 + lq*16);
      #pragma unroll
      for (int m = 0; m < 4; ++m)
        acc2[m] = MFMA(a[m], wb0, acc2[m]);
      if (kt < 5) wb0 = wbn;
    }
    float* res = (float*)(sm + A_Q);
    int col = w12*16 + l15;
    if (col < 180){
      float bias = projb[col];
      #pragma unroll
      for (int m = 0; m < 4; ++m)
        #pragma unroll
        for (int r = 0; r < 4; ++r)
          res[(m*16 + lq*4 + r)*180 + col] = acc2[m][r] + bias;
    }
  }
  __syncthreads();

  // ---- residual write (waves 0..7): out = RES + x (x from LN1 registers) ----
  if (w12 < 8){
    const float* res = (const float*)(sm + A_Q);
    const float4* rr = (const float4*)(res + myrow*180);
    float4* og = (float4*)(out + myglob);
    #pragma unroll
    for (int i = 0; i < 6; ++i){
      if (i < 5 || lq2 < 5){
        int c4 = lq2 + 8*i;
        float4 a = rr[c4];
        a.x += xv[i].x; a.y += xv[i].y; a.z += xv[i].z; a.w += xv[i].w;
        og[c4] = a;
      }
    }
  }
}

// ---------------- kernel 2: LN2 + MLP(fast GELU) + residual (1024 thr, 16 waves = 4/SIMD) ----
// UNCHANGED from the twice-measured ~223us configuration.
#define M_Y 0
#define M_G 25600   // 64 x 1552B

__global__ __launch_bounds__(1024, 1) void swin_mlp(
    const float* __restrict__ n2s, const float* __restrict__ n2b,
    const u16* __restrict__ ws, const float* __restrict__ b1, const float* __restrict__ b2,
    float* __restrict__ out){
  __shared__ __align__(16) char sm[124928];
  const int tid = threadIdx.x;
  const int w16 = tid >> 6, l = tid & 63, l15 = l & 15, lq = l >> 4;
  const size_t base = (size_t)blockIdx.x * (64*180);
  const f32x4 fz = {0.f, 0.f, 0.f, 0.f};
  float4 xv[3];                 // this thread's x2 slice, retained from LN2
  const int r4 = l & 3, lq4 = l >> 2;
  const int myrow = w16*4 + r4;

  // zero Y pad cols 180..191
  if (tid < 768){
    int row = tid / 12, col = 180 + tid % 12;
    *(u16*)(sm + M_Y + row*400 + col*2) = 0;
  }
  // ---- LN2: 16 waves x 4 rows, 16 lanes per row; x2 retained in registers ----
  {
    const float4* px = (const float4*)(out + base + (size_t)myrow*180);
    xv[0] = px[lq4];
    xv[1] = px[lq4 + 16];
    xv[2] = (lq4 < 13) ? px[lq4 + 32] : make_float4(0.f,0.f,0.f,0.f);
    float s = 0.f, ss = 0.f;
    #pragma unroll
    for (int i = 0; i < 3; ++i){
      s  += xv[i].x + xv[i].y + xv[i].z + xv[i].w;
      ss += xv[i].x*xv[i].x + xv[i].y*xv[i].y + xv[i].z*xv[i].z + xv[i].w*xv[i].w;
    }
    #pragma unroll
    for (int m = 4; m <= 32; m <<= 1){ s += __shfl_xor(s, m); ss += __shfl_xor(ss, m); }
    float mean = s * (1.f/180.f);
    float rstd = rsqrtf(ss * (1.f/180.f) - mean*mean + 1e-5f);
    u32* yr = (u32*)(sm + M_Y + myrow*400);
    const float4* s4 = (const float4*)n2s;
    const float4* b4 = (const float4*)n2b;
    #pragma unroll
    for (int i = 0; i < 3; ++i){
      if (i < 2 || lq4 < 13){
        int c4 = lq4 + 16*i;
        float4 sc = s4[c4], bi = b4[c4];
        float e0 = (xv[i].x - mean)*rstd*sc.x + bi.x;
        float e1 = (xv[i].y - mean)*rstd*sc.y + bi.y;
        float e2 = (xv[i].z - mean)*rstd*sc.z + bi.z;
        float e3 = (xv[i].w - mean)*rstd*sc.w + bi.w;
        yr[c4*2]     = pack2(e0, e1);
        yr[c4*2 + 1] = pack2(e2, e3);
      }
    }
  }
  __syncthreads();

  // ---- GEMM1 + fast GELU: wave w16 owns 3 nt (48 total = 768 cols); 1-deep prefetch ----
  {
    const int ntb = w16*3;
    f32x4 acc[4][3];
    #pragma unroll
    for (int m = 0; m < 4; ++m)
      #pragma unroll
      for (int i = 0; i < 3; ++i) acc[m][i] = fz;
    bf16x8 bcur[3];
    #pragma unroll
    for (int i = 0; i < 3; ++i)
      bcur[i] = *(const bf16x8*)(ws + OW1 + ((ntb+i)*6 + 0)*512 + l*8);
    #pragma unroll
    for (int kt = 0; kt < 6; ++kt){
      bf16x8 bnxt[3];
      if (kt < 5){
        #pragma unroll
        for (int i = 0; i < 3; ++i)
          bnxt[i] = *(const bf16x8*)(ws + OW1 + ((ntb+i)*6 + kt + 1)*512 + l*8);
      }
      bf16x8 a[4];
      #pragma unroll
      for (int m = 0; m < 4; ++m)
        a[m] = *(const bf16x8*)(sm + M_Y + (m*16 + l15)*400 + kt*64 + lq*16);
      #pragma unroll
      for (int m = 0; m < 4; ++m)
        #pragma unroll
        for (int i = 0; i < 3; ++i)
          acc[m][i] = MFMA(a[m], bcur[i], acc[m][i]);
      if (kt < 5){
        #pragma unroll
        for (int i = 0; i < 3; ++i) bcur[i] = bnxt[i];
      }
    }
    #pragma unroll
    for (int i = 0; i < 3; ++i){
      int gc = (ntb + i)*16 + l15;   // 0..767
      float bias = (gc < 720) ? b1[gc] : 0.f;
      #pragma unroll
      for (int m = 0; m < 4; ++m)
        #pragma unroll
        for (int r = 0; r < 4; ++r){
          float v = acc[m][i][r] + bias;
          float gel = (gc < 720) ? gelu_fast(v) : 0.f;
          *(u16*)(sm + M_G + (m*16 + lq*4 + r)*1552 + gc*2) = f2bf(gel);
        }
    }
  }
  __syncthreads();

  // ---- GEMM2: 23 kt; wave w16 owns 1 nt (of 16 padded) x 4 mt; 2-deep prefetch ----
  {
    f32x4 acc2[4];
    #pragma unroll
    for (int m = 0; m < 4; ++m) acc2[m] = fz;
    bf16x8 wb0, wb1;
    wb0 = *(const bf16x8*)(ws + OW2 + (w16*23 + 0)*512 + l*8);
    wb1 = *(const bf16x8*)(ws + OW2 + (w16*23 + 1)*512 + l*8);
    for (int kt = 0; kt < 23; ++kt){
      int ktn = (kt < 21) ? kt + 2 : 22;
      bf16x8 wbn = *(const bf16x8*)(ws + OW2 + (w16*23 + ktn)*512 + l*8);
      bf16x8 a[4];
      #pragma unroll
      for (int m = 0; m < 4; ++m)
        a[m] = *(const bf16x8*)(sm + M_G + (m*16 + l15)*1552 + kt*64 + lq*16);
      #pragma unroll
      for (int m = 0; m < 4; ++m)
        acc2[m] = MFMA(a[m], wb0, acc2[m]);
      wb0 = wb1; wb1 = wbn;
    }
    __syncthreads();   // all G reads done before RES overwrites it

    float* res = (float*)(sm + M_G);
    int col = w16*16 + l15;
    if (col < 180){
      float bias = b2[col];
      #pragma unroll
      for (int m = 0; m < 4; ++m)
        #pragma unroll
        for (int r = 0; r < 4; ++r)
          res[(m*16 + lq*4 + r)*180 + col] = acc2[m][r] + bias;
    }
  }
  __syncthreads();

  // ---- residual write: out = RES + x2 (x2 from LN2 registers, no global re-read) ----
  {
    const float* res = (const float*)(sm + M_G);
    const float4* rr = (const float4*)(res + myrow*180);
    float4* og = (float4*)(out + base + (size_t)myrow*180);
    float4 a0 = rr[lq4];
    a0.x += xv[0].x; a0.y += xv[0].y; a0.z += xv[0].z; a0.w += xv[0].w;
    og[lq4] = a0;
    float4 a1 = rr[lq4 + 16];
    a1.x += xv[1].x; a1.y += xv[1].y; a1.z += xv[1].z; a1.w += xv[1].w;
    og[lq4 + 16] = a1;
    if (lq4 < 13){
      float4 a2 = rr[lq4 + 32];
      a2.x += xv[2].x; a2.y += xv[2].y; a2.z += xv[2].z; a2.w += xv[2].w;
      og[lq4 + 32] = a2;
    }
  }
}

extern "C" void kernel_launch(void* const* d_in, const int* in_sizes, int n_in,
                              void* d_out, int out_size, void* d_ws, size_t ws_size,
                              hipStream_t stream){
  const float* x     = (const float*)d_in[0];
  const float* n1s   = (const float*)d_in[1];
  const float* n1b   = (const float*)d_in[2];
  const float* qkvw  = (const float*)d_in[3];
  const float* qkvb  = (const float*)d_in[4];
  const float* projw = (const float*)d_in[5];
  const float* projb = (const float*)d_in[6];
  const float* n2s   = (const float*)d_in[7];
  const float* n2b   = (const float*)d_in[8];
  const float* w1    = (const float*)d_in[9];
  const float* b1    = (const float*)d_in[10];
  const float* w2    = (const float*)d_in[11];
  const float* b2    = (const float*)d_in[12];
  float* outp = (float*)d_out;
  u16* wsp = (u16*)d_ws;

  swin_unpack<<<(NW_TOT + 255) / 256, 256, 0, stream>>>(qkvw, projw, w1, w2, wsp);
  swin_attn<<<4096, 768, 0, stream>>>(x, n1s, n1b, wsp, qkvb, projb, outp);
  swin_mlp<<<4096, 1024, 0, stream>>>(n2s, n2b, wsp, b1, b2, outp);
}